// Round 16
// baseline (317.982 us; speedup 1.0000x reference)
//
#include <hip/hip_runtime.h>
#include <math.h>

#define HW 65536
#define WID 256
#define HEI 256
#define NB 2
#define NFG 20
#define NMAP 40
#define CH 256
#define CSEG 21
#define TK 100
#define PARTS 32
#define PARTN (HW / PARTS)    // 2048
#define RPP (HEI / PARTS)     // 8 rows per part
#define CAND (PARTS * TK)     // 3200
#define MCH 13                // ceil(CAND/256)

__device__ __constant__ float c_GX[25] = {
  2.f,1.f,1e-6f,-1.f,-2.f,
  3.f,2.f,1e-6f,-2.f,-3.f,
  4.f,3.f,0.f,-3.f,-4.f,
  3.f,2.f,1e-6f,-2.f,-3.f,
  2.f,1.f,1e-6f,-1.f,-2.f};
__device__ __constant__ float c_GY[25] = {
  2.f,3.f,4.f,3.f,2.f,
  1.f,2.f,3.f,2.f,1.f,
  1e-6f,1e-6f,1e-6f,1e-6f,1e-6f,
  -1.f,-2.f,-3.f,-2.f,-1.f,
  -2.f,-3.f,-4.f,-3.f,-2.f};

// ---------------- K2a (fused seg+sobel): per-pixel softmax recomputed in-block,
// bit-identical to the former standalone k_seg (same expression order, same
// underflow shortcut); Sobel/quantize math bit-identical to the passing kernel.
// Key = gx^2+gy^2+1e-8 (monotone in mag). Bucket via sign logic + tan
// thresholds (endpoint/±0 semantics match atan2 intervals).
__global__ __launch_bounds__(256) void k_sobel(
    const float* __restrict__ seg_map, const float* __restrict__ label,
    unsigned char* __restrict__ qb, unsigned long long* __restrict__ keys) {
  int mapi = blockIdx.x / PARTS, part = blockIdx.x % PARTS;
  int tid = threadIdx.x;
  int row0 = part * RPP;
  int b = mapi / NFG, c = mapi % NFG;

  __shared__ double tile[RPP + 4][WID];       // 24576 B

  for (int r = 0; r < RPP + 4; ++r) {
    int gr = row0 - 2 + r;
    double val = 0.0;
    if (gr >= 0 && gr < HEI) {
      int p = gr * WID + tid;
      double x[CSEG];
      double m = -INFINITY;
      #pragma unroll
      for (int ch = 0; ch < CSEG; ++ch) {
        double v = (double)seg_map[(size_t)(b * CSEG + ch) * HW + p] * 1000.0;
        x[ch] = v;
        m = fmax(m, v);
      }
      double s = 0.0;
      #pragma unroll
      for (int ch = 0; ch < CSEG; ++ch) {
        double d = x[ch] - m;
        double e = (d < -746.0) ? 0.0 : exp(d);   // bit-identical to exp(d)
        x[ch] = e; s += e;
      }
      val = x[c + 1] / s;                         // softmax[...,c+1]
    }
    tile[r][tid] = val;
  }
  __syncthreads();

  double lab = (double)label[b * CSEG + c + 1];
  const double DIVQ = 3.1416 / 8.0;
  double u1 = tan(DIVQ);                 // tan(T1)
  double u3 = tan(3.0 * DIVQ);           // tan(T3)
  double w5 = tan(M_PI - 5.0 * DIVQ);    // tan(pi - T5)
  double w7 = tan(M_PI - 7.0 * DIVQ);    // tan(pi - T7)

  #pragma unroll
  for (int k = 0; k < RPP; ++k) {
    double gx = 0.0, gy = 0.0;
    #pragma unroll
    for (int dy = 0; dy < 5; ++dy) {
      #pragma unroll
      for (int dx = 0; dx < 5; ++dx) {
        int xx = tid + dx - 2;
        double v = (xx >= 0 && xx < WID) ? tile[k + dy][xx] : 0.0;
        gx += v * (double)c_GX[dy * 5 + dx];
        gy += v * (double)c_GY[dy * 5 + dx];
      }
    }
    gx *= lab; gy *= lab;
    double rad2 = gx * gx + gy * gy + 1e-8;    // same expr order as sqrt version
    int qv;
    if (gx > 0.0) {                    // o in (-pi/2, pi/2)
      double t1 = u1 * gx, t3 = u3 * gx;
      if (gy >= t3) qv = 1;            // [T3, pi/2)
      else if (gy >= t1) qv = 0;       // [T1, T3)
      else if (gy >= -t1) qv = 7;      // [-T1, T1)
      else if (gy >= -t3) qv = 6;      // [-T3, -T1)
      else qv = 5;                     // (-pi/2, -T3)
    } else if (gx < 0.0) {
      double ag = -gx;
      if (gy >= 0.0) {                 // o in (pi/2, pi]  (gy=+-0 -> o=+-pi -> q3)
        if (gy <= w7 * ag) qv = 3;     // [T7, pi]
        else if (gy <= w5 * ag) qv = 2;// [T5, T7)
        else qv = 1;                   // (pi/2, T5)
      } else {                         // o in (-pi, -pi/2)
        double ay = -gy;
        if (ay < w7 * ag) qv = 3;      // (-pi, -T7)
        else if (ay < w5 * ag) qv = 4; // [-T7, -T5)
        else qv = 5;                   // [-T5, -pi/2)
      }
    } else {                           // gx == +0 (never -0 here)
      if (gy > 0.0) qv = 1;            // o = pi/2 in [T3, T5)
      else if (gy < 0.0) qv = 5;       // o = -pi/2 in [-T5, -T3)
      else qv = 7;                     // atan2(+-0, +0) = +-0 -> [-T1, T1)
    }
    size_t gp = (size_t)mapi * HW + (size_t)(row0 + k) * WID + tid;
    keys[gp] = (unsigned long long)__double_as_longlong(rad2);
    qb[gp] = (unsigned char)qv;
  }
}

// ---------------- K2b: per-part exact top-100 over precomputed keys -------------
// Aggregated atomics, early exit, 3 barriers/round; LDS key mirror for the
// index-ordered extraction. Numpy argsort[::-1] tie semantics.
__global__ __launch_bounds__(256) void k_select(
    const unsigned long long* __restrict__ keys,
    unsigned long long* __restrict__ ckey, int* __restrict__ cidx) {
  int mapi = blockIdx.x / PARTS, part = blockIdx.x % PARTS;
  int tid = threadIdx.x;
  int lane = tid & 63, w = tid >> 6;
  const unsigned long long* kp = keys + (size_t)mapi * HW + (size_t)part * PARTN;

  __shared__ unsigned long long sk[PARTN];    // 16384 B
  __shared__ unsigned int hist4[4][256];      // 4096 B
  __shared__ int wtot[4];
  __shared__ int s_r, s_cnt, s_bsel, s_selcnt;
  __shared__ unsigned long long s_kv;

  unsigned long long mykey[RPP];
  #pragma unroll
  for (int k = 0; k < RPP; ++k) {
    unsigned long long key = kp[k * 256 + tid];
    mykey[k] = key;
    sk[k * 256 + tid] = key;
  }
  hist4[0][tid] = 0; hist4[1][tid] = 0; hist4[2][tid] = 0; hist4[3][tid] = 0;
  if (tid == 0) { s_r = TK; s_cnt = 0; }
  __syncthreads();

  // ---- radix select of the 100th-largest key (aggregated atomics, early exit)
  unsigned long long pfx = 0ull, msk = 0ull;
  int early = 0;
  for (int round = 0; round < 8; ++round) {
    int shift = 56 - 8 * round;
    int curb = -1; unsigned int curc = 0;
    #pragma unroll
    for (int k = 0; k < RPP; ++k) {
      unsigned long long key = mykey[k];
      int bk = ((key & msk) == pfx) ? (int)((key >> shift) & 0xFF) : -1;
      if (bk == curb) { ++curc; }
      else {
        if (curb >= 0) atomicAdd(&hist4[w][curb], curc);
        curb = bk; curc = 1;
      }
    }
    if (curb >= 0) atomicAdd(&hist4[w][curb], curc);
    __syncthreads();               // B1: atomics visible
    int r = s_r;
    int cnt = (int)(hist4[0][tid] + hist4[1][tid] + hist4[2][tid] + hist4[3][tid]);
    hist4[0][tid] = 0; hist4[1][tid] = 0; hist4[2][tid] = 0; hist4[3][tid] = 0;
    int v = cnt;
    #pragma unroll
    for (int off = 1; off < 64; off <<= 1) {   // wave inclusive SUFFIX scan
      int u = __shfl_down(v, off, 64);
      if (lane + off < 64) v += u;
    }
    if (lane == 0) wtot[w] = v;
    __syncthreads();               // B2: wtot visible
    int add = 0;
    for (int ww = w + 1; ww < 4; ++ww) add += wtot[ww];
    v += add;                      // inclusive suffix over all 256 bins
    if (v >= r && v - cnt < r) { s_bsel = tid; s_r = r - (v - cnt); s_selcnt = cnt; }
    __syncthreads();               // B3: s_bsel/s_r/s_selcnt visible
    pfx |= ((unsigned long long)s_bsel << shift);
    msk |= (0xFFull << shift);
    if (s_selcnt == 1) { early = 1; break; }   // cutoff prefix unique -> done
  }
  if (early) {
    #pragma unroll
    for (int k = 0; k < RPP; ++k)
      if ((mykey[k] & msk) == pfx) s_kv = mykey[k];   // exactly one writer
    __syncthreads();
  } else {
    if (tid == 0) s_kv = pfx;      // full 64-bit prefix = exact value
    __syncthreads();
  }
  unsigned long long kv = s_kv;
  int need_eq = s_r;               // >= 1

  // ---- emit candidates: strictly-greater (any order) + largest-index equals
  unsigned long long* outk = ckey + (size_t)mapi * CAND + (size_t)part * TK;
  int* outi = cidx + (size_t)mapi * CAND + (size_t)part * TK;
  int gbase = part * PARTN;
  const int CHN = PARTN / 256;     // 8, contiguous chunk per thread (index order)
  int base = tid * CHN;
  int myeq = 0;
  for (int k = 0; k < CHN; ++k) {
    unsigned long long key = sk[base + k];
    if (key > kv) {
      int slot = atomicAdd(&s_cnt, 1);
      outk[slot] = key; outi[slot] = gbase + base + k;
    } else if (key == kv) ++myeq;
  }
  int v2 = myeq;                   // ascending inclusive scan over 256 threads
  #pragma unroll
  for (int off = 1; off < 64; off <<= 1) {
    int u = __shfl_up(v2, off, 64);
    if (lane >= off) v2 += u;
  }
  if (lane == 63) wtot[w] = v2;
  __syncthreads();
  int addl = 0;
  for (int ww = 0; ww < w; ++ww) addl += wtot[ww];
  int incl = v2 + addl;
  int rank = incl - myeq;          // exclusive prefix = ascending-index rank
  int eqtot = wtot[0] + wtot[1] + wtot[2] + wtot[3];
  int lo = eqtot - need_eq;        // keep equals with rank >= lo (largest indices)
  int wb = TK - need_eq;
  for (int k = 0; k < CHN; ++k) {
    unsigned long long key = sk[base + k];
    if (key == kv) {
      if (rank >= lo) { outk[wb + rank - lo] = key; outi[wb + rank - lo] = gbase + base + k; }
      ++rank;
    }
  }
}

// ---------------- K3b: merge 3200 candidates -> exact global top-100 ------------
__global__ __launch_bounds__(256) void k_topk_merge(
    const unsigned long long* __restrict__ ckey,
    const int* __restrict__ cidx, int* __restrict__ pos) {
  int mapi = blockIdx.x, tid = threadIdx.x;
  int lane = tid & 63, w = tid >> 6;
  __shared__ unsigned long long k_[CAND];       // 25.6 KiB
  __shared__ int i_[CAND];                      // 12.8 KiB
  __shared__ int eqi[CAND];                     // 12.8 KiB
  __shared__ unsigned int hist4[4][256];
  __shared__ int wtot[4];
  __shared__ int s_r, s_cnt, s_eqn, s_bsel, s_selcnt, s_w2;
  __shared__ unsigned long long s_kv;
  for (int c = tid; c < CAND; c += 256) {
    k_[c] = ckey[(size_t)mapi * CAND + c];
    i_[c] = cidx[(size_t)mapi * CAND + c];
  }
  hist4[0][tid] = 0; hist4[1][tid] = 0; hist4[2][tid] = 0; hist4[3][tid] = 0;
  if (tid == 0) { s_r = TK; s_cnt = 0; s_eqn = 0; s_w2 = 0; }
  __syncthreads();
  unsigned long long pfx = 0ull, msk = 0ull;
  int early = 0;
  int mbase = tid * MCH;           // contiguous chunk -> equal keys form runs
  for (int round = 0; round < 8; ++round) {
    int shift = 56 - 8 * round;
    int curb = -1; unsigned int curc = 0;
    for (int t = 0; t < MCH; ++t) {
      int cc = mbase + t;
      int bk = -1;
      if (cc < CAND) {
        unsigned long long key = k_[cc];
        if ((key & msk) == pfx) bk = (int)((key >> shift) & 0xFF);
      }
      if (bk == curb) { ++curc; }
      else {
        if (curb >= 0) atomicAdd(&hist4[w][curb], curc);
        curb = bk; curc = 1;
      }
    }
    if (curb >= 0) atomicAdd(&hist4[w][curb], curc);
    __syncthreads();               // B1
    int r = s_r;
    int cnt = (int)(hist4[0][tid] + hist4[1][tid] + hist4[2][tid] + hist4[3][tid]);
    hist4[0][tid] = 0; hist4[1][tid] = 0; hist4[2][tid] = 0; hist4[3][tid] = 0;
    int v = cnt;
    #pragma unroll
    for (int off = 1; off < 64; off <<= 1) {
      int u = __shfl_down(v, off, 64);
      if (lane + off < 64) v += u;
    }
    if (lane == 0) wtot[w] = v;
    __syncthreads();               // B2
    int add = 0;
    for (int ww = w + 1; ww < 4; ++ww) add += wtot[ww];
    v += add;
    if (v >= r && v - cnt < r) { s_bsel = tid; s_r = r - (v - cnt); s_selcnt = cnt; }
    __syncthreads();               // B3
    pfx |= ((unsigned long long)s_bsel << shift);
    msk |= (0xFFull << shift);
    if (s_selcnt == 1) { early = 1; break; }
  }
  if (early) {
    for (int c = tid; c < CAND; c += 256)
      if ((k_[c] & msk) == pfx) s_kv = k_[c];
    __syncthreads();
  } else {
    if (tid == 0) s_kv = pfx;
    __syncthreads();
  }
  unsigned long long kv = s_kv;
  int need_eq = s_r;
  for (int c = tid; c < CAND; c += 256) {
    unsigned long long key = k_[c];
    if (key > kv) {
      int slot = atomicAdd(&s_cnt, 1);
      pos[mapi * TK + slot] = i_[c];            // set semantics; order irrelevant
    } else if (key == kv) {
      int e = atomicAdd(&s_eqn, 1);
      eqi[e] = i_[c];
    }
  }
  __syncthreads();
  int eqn = s_eqn;
  int wb = TK - need_eq;
  if (eqn == need_eq) {            // all equals belong
    for (int e = tid; e < eqn; e += 256) pos[mapi * TK + wb + e] = eqi[e];
    return;
  }
  // exact 2-round radix select of the need_eq-th largest INDEX among equals
  if (tid == 0) s_r = need_eq;
  __syncthreads();
  unsigned int ipfx = 0u, imsk = 0u;
  for (int round = 0; round < 2; ++round) {
    int shift = 8 * (1 - round);
    for (int e = tid; e < eqn; e += 256) {
      unsigned int iv = (unsigned int)eqi[e];
      if ((iv & imsk) == ipfx)
        atomicAdd(&hist4[w][(iv >> shift) & 0xFFu], 1u);
    }
    __syncthreads();               // B1
    int r = s_r;
    int cnt = (int)(hist4[0][tid] + hist4[1][tid] + hist4[2][tid] + hist4[3][tid]);
    hist4[0][tid] = 0; hist4[1][tid] = 0; hist4[2][tid] = 0; hist4[3][tid] = 0;
    int v = cnt;
    #pragma unroll
    for (int off = 1; off < 64; off <<= 1) {
      int u = __shfl_down(v, off, 64);
      if (lane + off < 64) v += u;
    }
    if (lane == 0) wtot[w] = v;
    __syncthreads();               // B2
    int add = 0;
    for (int ww = w + 1; ww < 4; ++ww) add += wtot[ww];
    v += add;
    if (v >= r && v - cnt < r) { s_bsel = tid; s_r = r - (v - cnt); }
    __syncthreads();               // B3
    ipfx |= ((unsigned int)s_bsel << shift);
    imsk |= (0xFFu << shift);
  }
  int thrIdx = (int)ipfx;          // need_eq-th largest index; distinct -> exact
  for (int e = tid; e < eqn; e += 256) {
    if (eqi[e] >= thrIdx) {
      int slot = atomicAdd(&s_w2, 1);
      pos[mapi * TK + wb + slot] = eqi[e];
    }
  }
}

// ---------------- K4: gather + per-column f64 softmax, one wave per softmax -----
__global__ __launch_bounds__(256) void k_gather(
    const float* __restrict__ dense_ft, const float* __restrict__ maskp,
    const unsigned char* __restrict__ qb, const int* __restrict__ pos,
    double* __restrict__ outs, double* __restrict__ ins,
    double* __restrict__ outs_m, double* __restrict__ ins_m,
    int* __restrict__ voutArr, int* __restrict__ vinArr) {
  int blk = blockIdx.x;
  int mapi = blk / TK, j = blk % TK;
  int b = mapi / NFG;
  int tid = threadIdx.x;
  int lane = tid & 63, w = tid >> 6;
  int p = pos[mapi * TK + j];
  int o = (int)qb[(size_t)mapi * HW + p] + 1;
  int mod4 = ((o & 3) == 0) ? 1 : 0;
  int horiz = (o == 2 || o == 6) ? 1 : 0;
  int po = (o < 4) ? 25 : -5;   // STEP*STEP : -STEP
  int pi = (o < 4) ? -5 : 1;
  int so = ((o & 1) == 0) ? -1 : 1;
  int si = -so;
  int out_idx = p + po * mod4 * WID + so * horiz;
  int in_idx  = p + pi * mod4 * WID + si * horiz;
  int ro = out_idx % 255; if (ro < 0) ro += 255;   // python floored mod
  int ri = in_idx  % 255; if (ri < 0) ri += 255;
  int vo = (ro != 0 && ro != 1 && out_idx > 0 && out_idx < HW - 1) ? 1 : 0;
  int vi = (ri != 0 && ri != 1 && in_idx  > 0 && in_idx  < HW - 1) ? 1 : 0;
  int oi = out_idx < 0 ? 0 : (out_idx > HW - 1 ? HW - 1 : out_idx);
  int ii = in_idx  < 0 ? 0 : (in_idx  > HW - 1 ? HW - 1 : in_idx);
  if (tid == 0) { voutArr[mapi * TK + j] = vo; vinArr[mapi * TK + j] = vi; }

  if (w < 2) {
    int idx = (w == 0) ? oi : ii;
    double x[4];
    double mx = -INFINITY;
    #pragma unroll
    for (int q = 0; q < 4; ++q) {
      x[q] = (double)dense_ft[(size_t)(b * CH + lane + 64 * q) * HW + idx];
      mx = fmax(mx, x[q]);
    }
    #pragma unroll
    for (int off = 1; off < 64; off <<= 1) mx = fmax(mx, __shfl_xor(mx, off, 64));
    double e[4], s = 0.0;
    #pragma unroll
    for (int q = 0; q < 4; ++q) { e[q] = exp(x[q] - mx); s += e[q]; }
    #pragma unroll
    for (int off = 1; off < 64; off <<= 1) s += __shfl_xor(s, off, 64);
    double* dst = ((w == 0) ? outs : ins) + ((size_t)mapi * TK + j) * CH;
    #pragma unroll
    for (int q = 0; q < 4; ++q) dst[lane + 64 * q] = e[q] / s;
  } else {
    int idx = (w == 2) ? oi : ii;
    double y = (lane < CSEG) ? (double)maskp[(size_t)(b * CSEG + lane) * HW + idx]
                             : -INFINITY;
    double mx = y;
    #pragma unroll
    for (int off = 1; off < 64; off <<= 1) mx = fmax(mx, __shfl_xor(mx, off, 64));
    double e = (lane < CSEG) ? exp(y - mx) : 0.0;
    double s = e;
    #pragma unroll
    for (int off = 1; off < 64; off <<= 1) s += __shfl_xor(s, off, 64);
    if (lane < CSEG)
      (((w == 2) ? outs_m : ins_m) + ((size_t)mapi * TK + j) * CSEG)[lane] = e / s;
  }
}

// ---------------- K5: per-map statistics + beacon in f64 (sim never materialized)
__global__ __launch_bounds__(256) void k_stats(
    const double* __restrict__ outs, const double* __restrict__ ins,
    const double* __restrict__ outs_m, const double* __restrict__ ins_m,
    const int* __restrict__ voutArr, const int* __restrict__ vinArr,
    const float* __restrict__ label, double* __restrict__ lossmap) {
  int mapi = blockIdx.x, tid = threadIdx.x;
  int b = mapi / NFG, c = mapi % NFG;
  __shared__ double fvo[TK], fvi[TK];
  __shared__ double avi[CH], avo[CH], avim[CSEG], avom[CSEG];
  __shared__ double rm[TK], cm[TK], rmm[TK], cmm[TK];
  __shared__ double s_sfvo, s_sfvi;
  if (tid < TK) {
    fvo[tid] = (double)voutArr[mapi * TK + tid];
    fvi[tid] = (double)vinArr[mapi * TK + tid];
  }
  __syncthreads();
  if (tid == 0) {
    double a = 0.0, d = 0.0;
    for (int j2 = 0; j2 < TK; ++j2) { a += fvo[j2]; d += fvi[j2]; }
    s_sfvo = a; s_sfvi = d;
  }
  const double* OUT  = outs   + (size_t)mapi * TK * CH;
  const double* IN   = ins    + (size_t)mapi * TK * CH;
  const double* OUTm = outs_m + (size_t)mapi * TK * CSEG;
  const double* INm  = ins_m  + (size_t)mapi * TK * CSEG;
  {
    double a = 0.0, d = 0.0;
    for (int j2 = 0; j2 < TK; ++j2) {
      a += IN[j2 * CH + tid] * fvi[j2];
      d += OUT[j2 * CH + tid] * fvo[j2];
    }
    avi[tid] = a; avo[tid] = d;
  }
  if (tid < CSEG) {
    double a = 0.0, d = 0.0;
    for (int j2 = 0; j2 < TK; ++j2) {
      a += INm[j2 * CSEG + tid] * fvi[j2];
      d += OUTm[j2 * CSEG + tid] * fvo[j2];
    }
    avim[tid] = a; avom[tid] = d;
  }
  __syncthreads();
  double ci = fmax(s_sfvi, 1.0), co = fmax(s_sfvo, 1.0);
  if (tid < TK) {
    double d1 = 0.0, d2 = 0.0, d3 = 0.0, d4 = 0.0;
    for (int e = 0; e < CH; ++e) { d1 += OUT[tid * CH + e] * avi[e]; d2 += IN[tid * CH + e] * avo[e]; }
    for (int e = 0; e < CSEG; ++e) { d3 += OUTm[tid * CSEG + e] * avim[e]; d4 += INm[tid * CSEG + e] * avom[e]; }
    rm[tid] = d1 / ci; cm[tid] = d2 / co; rmm[tid] = d3 / ci; cmm[tid] = d4 / co;
  }
  __syncthreads();
  if (tid == 0) {
    double g = 0.0, gm = 0.0;
    for (int e = 0; e < CH; ++e) g += avo[e] * avi[e];
    for (int e = 0; e < CSEG; ++e) gm += avom[e] * avim[e];
    double den = fmax(s_sfvo * s_sfvi, 1.0);
    g /= den; gm /= den;
    double loss = 0.0;
    { // row beacon: sgn_mask = rmm>gm, sgn_dense = rm>g, vals = rm, v = fvo
      double s[4] = {0, 0, 0, 0}, cn[4] = {0, 0, 0, 0};
      for (int j2 = 0; j2 < TK; ++j2) {
        int smv = rmm[j2] > gm;
        int dmv = rm[j2] > g;
        int cat = smv ? (dmv ? 3 : 0) : (dmv ? 1 : 2);  // FP,FN,TP,TN = 0,1,2,3
        s[cat] += rm[j2] * fvo[j2];
        cn[cat] += fvo[j2];
      }
      const double sg[4] = {-1.0, 1.0, 1.0, -1.0};
      for (int t = 0; t < 4; ++t)
        if (cn[t] > 0.0) loss += sg[t] * (s[t] / fmax(cn[t], 1.0));
    }
    { // col beacon: sgn_mask = cmm>gm, sgn_dense = cm>g, vals = cm, v = fvi
      double s[4] = {0, 0, 0, 0}, cn[4] = {0, 0, 0, 0};
      for (int j2 = 0; j2 < TK; ++j2) {
        int smv = cmm[j2] > gm;
        int dmv = cm[j2] > g;
        int cat = smv ? (dmv ? 3 : 0) : (dmv ? 1 : 2);
        s[cat] += cm[j2] * fvi[j2];
        cn[cat] += fvi[j2];
      }
      const double sg[4] = {-1.0, 1.0, 1.0, -1.0};
      for (int t = 0; t < 4; ++t)
        if (cn[t] > 0.0) loss += sg[t] * (s[t] / fmax(cn[t], 1.0));
    }
    float lab = label[b * CSEG + c + 1];
    double gate = (s_sfvi >= 10.0 && s_sfvo >= 10.0 && lab > 0.f) ? 1.0 : 0.0;
    lossmap[mapi] = loss * gate;
  }
}

// ---------------- K6: deterministic ordered final sum --------------------------
__global__ __launch_bounds__(64) void k_final(const double* __restrict__ lossmap,
                                              float* __restrict__ out) {
  if (threadIdx.x == 0 && blockIdx.x == 0) {
    double s = 0.0;
    for (int i = 0; i < NMAP; ++i) s += lossmap[i];
    out[0] = (float)s;
  }
}

extern "C" void kernel_launch(void* const* d_in, const int* in_sizes, int n_in,
                              void* d_out, int out_size, void* d_ws, size_t ws_size,
                              hipStream_t stream) {
  const float* seg_map  = (const float*)d_in[0];
  const float* dense_ft = (const float*)d_in[1];
  const float* maskp    = (const float*)d_in[2];
  const float* label    = (const float*)d_in[3];
  float* outp = (float*)d_out;

  char* w = (char*)d_ws;
  unsigned long long* keys = (unsigned long long*)w; w += (size_t)NMAP * HW * 8;
  double* outs   = (double*)w;            w += (size_t)NMAP * TK * CH * 8;
  double* ins    = (double*)w;            w += (size_t)NMAP * TK * CH * 8;
  double* outs_m = (double*)w;            w += (size_t)NMAP * TK * CSEG * 8;
  double* ins_m  = (double*)w;            w += (size_t)NMAP * TK * CSEG * 8;
  double* lossmap = (double*)w;           w += (size_t)NMAP * 8;
  unsigned long long* ckey = (unsigned long long*)w; w += (size_t)NMAP * CAND * 8;
  int* cidx = (int*)w;                    w += (size_t)NMAP * CAND * 4;
  int* pos  = (int*)w;                    w += (size_t)NMAP * TK * 4;
  int* vout = (int*)w;                    w += (size_t)NMAP * TK * 4;
  int* vin  = (int*)w;                    w += (size_t)NMAP * TK * 4;
  unsigned char* qb = (unsigned char*)w;  w += (size_t)NMAP * HW;

  k_sobel<<<NMAP * PARTS, 256, 0, stream>>>(seg_map, label, qb, keys);
  k_select<<<NMAP * PARTS, 256, 0, stream>>>(keys, ckey, cidx);
  k_topk_merge<<<NMAP, 256, 0, stream>>>(ckey, cidx, pos);
  k_gather<<<NMAP * TK, 256, 0, stream>>>(dense_ft, maskp, qb, pos, outs, ins,
                                          outs_m, ins_m, vout, vin);
  k_stats<<<NMAP, 256, 0, stream>>>(outs, ins, outs_m, ins_m, vout, vin, label, lossmap);
  k_final<<<1, 64, 0, stream>>>(lossmap, outp);
}

// Round 17
// 262.449 us; speedup vs baseline: 1.2116x; 1.2116x over previous
//
#include <hip/hip_runtime.h>
#include <math.h>

#define HW 65536
#define WID 256
#define HEI 256
#define NB 2
#define NFG 20
#define NMAP 40
#define CH 256
#define CSEG 21
#define TK 100
#define PARTS 32
#define PARTN (HW / PARTS)    // 2048
#define RPP (HEI / PARTS)     // 8 rows per part
#define CAND (PARTS * TK)     // 3200
#define MCH 13                // ceil(CAND/256)

__device__ __constant__ float c_GX[25] = {
  2.f,1.f,1e-6f,-1.f,-2.f,
  3.f,2.f,1e-6f,-2.f,-3.f,
  4.f,3.f,0.f,-3.f,-4.f,
  3.f,2.f,1e-6f,-2.f,-3.f,
  2.f,1.f,1e-6f,-1.f,-2.f};
__device__ __constant__ float c_GY[25] = {
  2.f,3.f,4.f,3.f,2.f,
  1.f,2.f,3.f,2.f,1.f,
  1e-6f,1e-6f,1e-6f,1e-6f,1e-6f,
  -1.f,-2.f,-3.f,-2.f,-1.f,
  -2.f,-3.f,-4.f,-3.f,-2.f};

// ---------------- K2a (fused seg+sobel): ARRAY-FREE two-pass softmax per pixel.
// Pass 1: channel max. Pass 2: recompute v (same load+mul -> bit-identical),
// accumulate s in channel order, capture e at ch==c+1. Arithmetic sequence
// identical to the former k_seg -> bit-identical tile values. Sobel/quantize
// math bit-identical to the passing kernel. Key = gx^2+gy^2+1e-8.
__global__ __launch_bounds__(256) void k_sobel(
    const float* __restrict__ seg_map, const float* __restrict__ label,
    unsigned char* __restrict__ qb, unsigned long long* __restrict__ keys) {
  int mapi = blockIdx.x / PARTS, part = blockIdx.x % PARTS;
  int tid = threadIdx.x;
  int row0 = part * RPP;
  int b = mapi / NFG, c = mapi % NFG;

  __shared__ double tile[RPP + 4][WID];       // 24576 B

  for (int r = 0; r < RPP + 4; ++r) {
    int gr = row0 - 2 + r;
    double val = 0.0;
    if (gr >= 0 && gr < HEI) {
      int p = gr * WID + tid;
      const float* sp = seg_map + (size_t)b * CSEG * HW + p;
      double m = -INFINITY;
      #pragma unroll
      for (int ch = 0; ch < CSEG; ++ch) {
        double v = (double)sp[(size_t)ch * HW] * 1000.0;
        m = fmax(m, v);
      }
      double s = 0.0, num = 0.0;
      #pragma unroll
      for (int ch = 0; ch < CSEG; ++ch) {
        double v = (double)sp[(size_t)ch * HW] * 1000.0;   // bit-identical reload
        double d = v - m;
        double e = (d < -746.0) ? 0.0 : exp(d);            // bit-identical to exp(d)
        s += e;
        if (ch == c + 1) num = e;
      }
      val = num / s;                                       // softmax[...,c+1]
    }
    tile[r][tid] = val;
  }
  __syncthreads();

  double lab = (double)label[b * CSEG + c + 1];
  const double DIVQ = 3.1416 / 8.0;
  double u1 = tan(DIVQ);                 // tan(T1)
  double u3 = tan(3.0 * DIVQ);           // tan(T3)
  double w5 = tan(M_PI - 5.0 * DIVQ);    // tan(pi - T5)
  double w7 = tan(M_PI - 7.0 * DIVQ);    // tan(pi - T7)

  #pragma unroll
  for (int k = 0; k < RPP; ++k) {
    double gx = 0.0, gy = 0.0;
    #pragma unroll
    for (int dy = 0; dy < 5; ++dy) {
      #pragma unroll
      for (int dx = 0; dx < 5; ++dx) {
        int xx = tid + dx - 2;
        double v = (xx >= 0 && xx < WID) ? tile[k + dy][xx] : 0.0;
        gx += v * (double)c_GX[dy * 5 + dx];
        gy += v * (double)c_GY[dy * 5 + dx];
      }
    }
    gx *= lab; gy *= lab;
    double rad2 = gx * gx + gy * gy + 1e-8;    // same expr order as sqrt version
    int qv;
    if (gx > 0.0) {                    // o in (-pi/2, pi/2)
      double t1 = u1 * gx, t3 = u3 * gx;
      if (gy >= t3) qv = 1;            // [T3, pi/2)
      else if (gy >= t1) qv = 0;       // [T1, T3)
      else if (gy >= -t1) qv = 7;      // [-T1, T1)
      else if (gy >= -t3) qv = 6;      // [-T3, -T1)
      else qv = 5;                     // (-pi/2, -T3)
    } else if (gx < 0.0) {
      double ag = -gx;
      if (gy >= 0.0) {                 // o in (pi/2, pi]  (gy=+-0 -> o=+-pi -> q3)
        if (gy <= w7 * ag) qv = 3;     // [T7, pi]
        else if (gy <= w5 * ag) qv = 2;// [T5, T7)
        else qv = 1;                   // (pi/2, T5)
      } else {                         // o in (-pi, -pi/2)
        double ay = -gy;
        if (ay < w7 * ag) qv = 3;      // (-pi, -T7)
        else if (ay < w5 * ag) qv = 4; // [-T7, -T5)
        else qv = 5;                   // [-T5, -pi/2)
      }
    } else {                           // gx == +0 (never -0 here)
      if (gy > 0.0) qv = 1;            // o = pi/2 in [T3, T5)
      else if (gy < 0.0) qv = 5;       // o = -pi/2 in [-T5, -T3)
      else qv = 7;                     // atan2(+-0, +0) = +-0 -> [-T1, T1)
    }
    size_t gp = (size_t)mapi * HW + (size_t)(row0 + k) * WID + tid;
    keys[gp] = (unsigned long long)__double_as_longlong(rad2);
    qb[gp] = (unsigned char)qv;
  }
}

// ---------------- K2b: per-part exact top-100 over precomputed keys -------------
// Aggregated atomics, early exit, 3 barriers/round; LDS key mirror for the
// index-ordered extraction. Numpy argsort[::-1] tie semantics.
__global__ __launch_bounds__(256) void k_select(
    const unsigned long long* __restrict__ keys,
    unsigned long long* __restrict__ ckey, int* __restrict__ cidx) {
  int mapi = blockIdx.x / PARTS, part = blockIdx.x % PARTS;
  int tid = threadIdx.x;
  int lane = tid & 63, w = tid >> 6;
  const unsigned long long* kp = keys + (size_t)mapi * HW + (size_t)part * PARTN;

  __shared__ unsigned long long sk[PARTN];    // 16384 B
  __shared__ unsigned int hist4[4][256];      // 4096 B
  __shared__ int wtot[4];
  __shared__ int s_r, s_cnt, s_bsel, s_selcnt;
  __shared__ unsigned long long s_kv;

  unsigned long long mykey[RPP];
  #pragma unroll
  for (int k = 0; k < RPP; ++k) {
    unsigned long long key = kp[k * 256 + tid];
    mykey[k] = key;
    sk[k * 256 + tid] = key;
  }
  hist4[0][tid] = 0; hist4[1][tid] = 0; hist4[2][tid] = 0; hist4[3][tid] = 0;
  if (tid == 0) { s_r = TK; s_cnt = 0; }
  __syncthreads();

  // ---- radix select of the 100th-largest key (aggregated atomics, early exit)
  unsigned long long pfx = 0ull, msk = 0ull;
  int early = 0;
  for (int round = 0; round < 8; ++round) {
    int shift = 56 - 8 * round;
    int curb = -1; unsigned int curc = 0;
    #pragma unroll
    for (int k = 0; k < RPP; ++k) {
      unsigned long long key = mykey[k];
      int bk = ((key & msk) == pfx) ? (int)((key >> shift) & 0xFF) : -1;
      if (bk == curb) { ++curc; }
      else {
        if (curb >= 0) atomicAdd(&hist4[w][curb], curc);
        curb = bk; curc = 1;
      }
    }
    if (curb >= 0) atomicAdd(&hist4[w][curb], curc);
    __syncthreads();               // B1: atomics visible
    int r = s_r;
    int cnt = (int)(hist4[0][tid] + hist4[1][tid] + hist4[2][tid] + hist4[3][tid]);
    hist4[0][tid] = 0; hist4[1][tid] = 0; hist4[2][tid] = 0; hist4[3][tid] = 0;
    int v = cnt;
    #pragma unroll
    for (int off = 1; off < 64; off <<= 1) {   // wave inclusive SUFFIX scan
      int u = __shfl_down(v, off, 64);
      if (lane + off < 64) v += u;
    }
    if (lane == 0) wtot[w] = v;
    __syncthreads();               // B2: wtot visible
    int add = 0;
    for (int ww = w + 1; ww < 4; ++ww) add += wtot[ww];
    v += add;                      // inclusive suffix over all 256 bins
    if (v >= r && v - cnt < r) { s_bsel = tid; s_r = r - (v - cnt); s_selcnt = cnt; }
    __syncthreads();               // B3: s_bsel/s_r/s_selcnt visible
    pfx |= ((unsigned long long)s_bsel << shift);
    msk |= (0xFFull << shift);
    if (s_selcnt == 1) { early = 1; break; }   // cutoff prefix unique -> done
  }
  if (early) {
    #pragma unroll
    for (int k = 0; k < RPP; ++k)
      if ((mykey[k] & msk) == pfx) s_kv = mykey[k];   // exactly one writer
    __syncthreads();
  } else {
    if (tid == 0) s_kv = pfx;      // full 64-bit prefix = exact value
    __syncthreads();
  }
  unsigned long long kv = s_kv;
  int need_eq = s_r;               // >= 1

  // ---- emit candidates: strictly-greater (any order) + largest-index equals
  unsigned long long* outk = ckey + (size_t)mapi * CAND + (size_t)part * TK;
  int* outi = cidx + (size_t)mapi * CAND + (size_t)part * TK;
  int gbase = part * PARTN;
  const int CHN = PARTN / 256;     // 8, contiguous chunk per thread (index order)
  int base = tid * CHN;
  int myeq = 0;
  for (int k = 0; k < CHN; ++k) {
    unsigned long long key = sk[base + k];
    if (key > kv) {
      int slot = atomicAdd(&s_cnt, 1);
      outk[slot] = key; outi[slot] = gbase + base + k;
    } else if (key == kv) ++myeq;
  }
  int v2 = myeq;                   // ascending inclusive scan over 256 threads
  #pragma unroll
  for (int off = 1; off < 64; off <<= 1) {
    int u = __shfl_up(v2, off, 64);
    if (lane >= off) v2 += u;
  }
  if (lane == 63) wtot[w] = v2;
  __syncthreads();
  int addl = 0;
  for (int ww = 0; ww < w; ++ww) addl += wtot[ww];
  int incl = v2 + addl;
  int rank = incl - myeq;          // exclusive prefix = ascending-index rank
  int eqtot = wtot[0] + wtot[1] + wtot[2] + wtot[3];
  int lo = eqtot - need_eq;        // keep equals with rank >= lo (largest indices)
  int wb = TK - need_eq;
  for (int k = 0; k < CHN; ++k) {
    unsigned long long key = sk[base + k];
    if (key == kv) {
      if (rank >= lo) { outk[wb + rank - lo] = key; outi[wb + rank - lo] = gbase + base + k; }
      ++rank;
    }
  }
}

// ---------------- K3b: merge 3200 candidates -> exact global top-100 ------------
__global__ __launch_bounds__(256) void k_topk_merge(
    const unsigned long long* __restrict__ ckey,
    const int* __restrict__ cidx, int* __restrict__ pos) {
  int mapi = blockIdx.x, tid = threadIdx.x;
  int lane = tid & 63, w = tid >> 6;
  __shared__ unsigned long long k_[CAND];       // 25.6 KiB
  __shared__ int i_[CAND];                      // 12.8 KiB
  __shared__ int eqi[CAND];                     // 12.8 KiB
  __shared__ unsigned int hist4[4][256];
  __shared__ int wtot[4];
  __shared__ int s_r, s_cnt, s_eqn, s_bsel, s_selcnt, s_w2;
  __shared__ unsigned long long s_kv;
  for (int c = tid; c < CAND; c += 256) {
    k_[c] = ckey[(size_t)mapi * CAND + c];
    i_[c] = cidx[(size_t)mapi * CAND + c];
  }
  hist4[0][tid] = 0; hist4[1][tid] = 0; hist4[2][tid] = 0; hist4[3][tid] = 0;
  if (tid == 0) { s_r = TK; s_cnt = 0; s_eqn = 0; s_w2 = 0; }
  __syncthreads();
  unsigned long long pfx = 0ull, msk = 0ull;
  int early = 0;
  int mbase = tid * MCH;           // contiguous chunk -> equal keys form runs
  for (int round = 0; round < 8; ++round) {
    int shift = 56 - 8 * round;
    int curb = -1; unsigned int curc = 0;
    for (int t = 0; t < MCH; ++t) {
      int cc = mbase + t;
      int bk = -1;
      if (cc < CAND) {
        unsigned long long key = k_[cc];
        if ((key & msk) == pfx) bk = (int)((key >> shift) & 0xFF);
      }
      if (bk == curb) { ++curc; }
      else {
        if (curb >= 0) atomicAdd(&hist4[w][curb], curc);
        curb = bk; curc = 1;
      }
    }
    if (curb >= 0) atomicAdd(&hist4[w][curb], curc);
    __syncthreads();               // B1
    int r = s_r;
    int cnt = (int)(hist4[0][tid] + hist4[1][tid] + hist4[2][tid] + hist4[3][tid]);
    hist4[0][tid] = 0; hist4[1][tid] = 0; hist4[2][tid] = 0; hist4[3][tid] = 0;
    int v = cnt;
    #pragma unroll
    for (int off = 1; off < 64; off <<= 1) {
      int u = __shfl_down(v, off, 64);
      if (lane + off < 64) v += u;
    }
    if (lane == 0) wtot[w] = v;
    __syncthreads();               // B2
    int add = 0;
    for (int ww = w + 1; ww < 4; ++ww) add += wtot[ww];
    v += add;
    if (v >= r && v - cnt < r) { s_bsel = tid; s_r = r - (v - cnt); s_selcnt = cnt; }
    __syncthreads();               // B3
    pfx |= ((unsigned long long)s_bsel << shift);
    msk |= (0xFFull << shift);
    if (s_selcnt == 1) { early = 1; break; }
  }
  if (early) {
    for (int c = tid; c < CAND; c += 256)
      if ((k_[c] & msk) == pfx) s_kv = k_[c];
    __syncthreads();
  } else {
    if (tid == 0) s_kv = pfx;
    __syncthreads();
  }
  unsigned long long kv = s_kv;
  int need_eq = s_r;
  for (int c = tid; c < CAND; c += 256) {
    unsigned long long key = k_[c];
    if (key > kv) {
      int slot = atomicAdd(&s_cnt, 1);
      pos[mapi * TK + slot] = i_[c];            // set semantics; order irrelevant
    } else if (key == kv) {
      int e = atomicAdd(&s_eqn, 1);
      eqi[e] = i_[c];
    }
  }
  __syncthreads();
  int eqn = s_eqn;
  int wb = TK - need_eq;
  if (eqn == need_eq) {            // all equals belong
    for (int e = tid; e < eqn; e += 256) pos[mapi * TK + wb + e] = eqi[e];
    return;
  }
  // exact 2-round radix select of the need_eq-th largest INDEX among equals
  if (tid == 0) s_r = need_eq;
  __syncthreads();
  unsigned int ipfx = 0u, imsk = 0u;
  for (int round = 0; round < 2; ++round) {
    int shift = 8 * (1 - round);
    for (int e = tid; e < eqn; e += 256) {
      unsigned int iv = (unsigned int)eqi[e];
      if ((iv & imsk) == ipfx)
        atomicAdd(&hist4[w][(iv >> shift) & 0xFFu], 1u);
    }
    __syncthreads();               // B1
    int r = s_r;
    int cnt = (int)(hist4[0][tid] + hist4[1][tid] + hist4[2][tid] + hist4[3][tid]);
    hist4[0][tid] = 0; hist4[1][tid] = 0; hist4[2][tid] = 0; hist4[3][tid] = 0;
    int v = cnt;
    #pragma unroll
    for (int off = 1; off < 64; off <<= 1) {
      int u = __shfl_down(v, off, 64);
      if (lane + off < 64) v += u;
    }
    if (lane == 0) wtot[w] = v;
    __syncthreads();               // B2
    int add = 0;
    for (int ww = w + 1; ww < 4; ++ww) add += wtot[ww];
    v += add;
    if (v >= r && v - cnt < r) { s_bsel = tid; s_r = r - (v - cnt); }
    __syncthreads();               // B3
    ipfx |= ((unsigned int)s_bsel << shift);
    imsk |= (0xFFu << shift);
  }
  int thrIdx = (int)ipfx;          // need_eq-th largest index; distinct -> exact
  for (int e = tid; e < eqn; e += 256) {
    if (eqi[e] >= thrIdx) {
      int slot = atomicAdd(&s_w2, 1);
      pos[mapi * TK + wb + slot] = eqi[e];
    }
  }
}

// ---------------- K4: gather + per-column f64 softmax, one wave per softmax -----
__global__ __launch_bounds__(256) void k_gather(
    const float* __restrict__ dense_ft, const float* __restrict__ maskp,
    const unsigned char* __restrict__ qb, const int* __restrict__ pos,
    double* __restrict__ outs, double* __restrict__ ins,
    double* __restrict__ outs_m, double* __restrict__ ins_m,
    int* __restrict__ voutArr, int* __restrict__ vinArr) {
  int blk = blockIdx.x;
  int mapi = blk / TK, j = blk % TK;
  int b = mapi / NFG;
  int tid = threadIdx.x;
  int lane = tid & 63, w = tid >> 6;
  int p = pos[mapi * TK + j];
  int o = (int)qb[(size_t)mapi * HW + p] + 1;
  int mod4 = ((o & 3) == 0) ? 1 : 0;
  int horiz = (o == 2 || o == 6) ? 1 : 0;
  int po = (o < 4) ? 25 : -5;   // STEP*STEP : -STEP
  int pi = (o < 4) ? -5 : 1;
  int so = ((o & 1) == 0) ? -1 : 1;
  int si = -so;
  int out_idx = p + po * mod4 * WID + so * horiz;
  int in_idx  = p + pi * mod4 * WID + si * horiz;
  int ro = out_idx % 255; if (ro < 0) ro += 255;   // python floored mod
  int ri = in_idx  % 255; if (ri < 0) ri += 255;
  int vo = (ro != 0 && ro != 1 && out_idx > 0 && out_idx < HW - 1) ? 1 : 0;
  int vi = (ri != 0 && ri != 1 && in_idx  > 0 && in_idx  < HW - 1) ? 1 : 0;
  int oi = out_idx < 0 ? 0 : (out_idx > HW - 1 ? HW - 1 : out_idx);
  int ii = in_idx  < 0 ? 0 : (in_idx  > HW - 1 ? HW - 1 : in_idx);
  if (tid == 0) { voutArr[mapi * TK + j] = vo; vinArr[mapi * TK + j] = vi; }

  if (w < 2) {
    int idx = (w == 0) ? oi : ii;
    double x[4];
    double mx = -INFINITY;
    #pragma unroll
    for (int q = 0; q < 4; ++q) {
      x[q] = (double)dense_ft[(size_t)(b * CH + lane + 64 * q) * HW + idx];
      mx = fmax(mx, x[q]);
    }
    #pragma unroll
    for (int off = 1; off < 64; off <<= 1) mx = fmax(mx, __shfl_xor(mx, off, 64));
    double e[4], s = 0.0;
    #pragma unroll
    for (int q = 0; q < 4; ++q) { e[q] = exp(x[q] - mx); s += e[q]; }
    #pragma unroll
    for (int off = 1; off < 64; off <<= 1) s += __shfl_xor(s, off, 64);
    double* dst = ((w == 0) ? outs : ins) + ((size_t)mapi * TK + j) * CH;
    #pragma unroll
    for (int q = 0; q < 4; ++q) dst[lane + 64 * q] = e[q] / s;
  } else {
    int idx = (w == 2) ? oi : ii;
    double y = (lane < CSEG) ? (double)maskp[(size_t)(b * CSEG + lane) * HW + idx]
                             : -INFINITY;
    double mx = y;
    #pragma unroll
    for (int off = 1; off < 64; off <<= 1) mx = fmax(mx, __shfl_xor(mx, off, 64));
    double e = (lane < CSEG) ? exp(y - mx) : 0.0;
    double s = e;
    #pragma unroll
    for (int off = 1; off < 64; off <<= 1) s += __shfl_xor(s, off, 64);
    if (lane < CSEG)
      (((w == 2) ? outs_m : ins_m) + ((size_t)mapi * TK + j) * CSEG)[lane] = e / s;
  }
}

// ---------------- K5: per-map statistics + beacon in f64 (sim never materialized)
__global__ __launch_bounds__(256) void k_stats(
    const double* __restrict__ outs, const double* __restrict__ ins,
    const double* __restrict__ outs_m, const double* __restrict__ ins_m,
    const int* __restrict__ voutArr, const int* __restrict__ vinArr,
    const float* __restrict__ label, double* __restrict__ lossmap) {
  int mapi = blockIdx.x, tid = threadIdx.x;
  int b = mapi / NFG, c = mapi % NFG;
  __shared__ double fvo[TK], fvi[TK];
  __shared__ double avi[CH], avo[CH], avim[CSEG], avom[CSEG];
  __shared__ double rm[TK], cm[TK], rmm[TK], cmm[TK];
  __shared__ double s_sfvo, s_sfvi;
  if (tid < TK) {
    fvo[tid] = (double)voutArr[mapi * TK + tid];
    fvi[tid] = (double)vinArr[mapi * TK + tid];
  }
  __syncthreads();
  if (tid == 0) {
    double a = 0.0, d = 0.0;
    for (int j2 = 0; j2 < TK; ++j2) { a += fvo[j2]; d += fvi[j2]; }
    s_sfvo = a; s_sfvi = d;
  }
  const double* OUT  = outs   + (size_t)mapi * TK * CH;
  const double* IN   = ins    + (size_t)mapi * TK * CH;
  const double* OUTm = outs_m + (size_t)mapi * TK * CSEG;
  const double* INm  = ins_m  + (size_t)mapi * TK * CSEG;
  {
    double a = 0.0, d = 0.0;
    for (int j2 = 0; j2 < TK; ++j2) {
      a += IN[j2 * CH + tid] * fvi[j2];
      d += OUT[j2 * CH + tid] * fvo[j2];
    }
    avi[tid] = a; avo[tid] = d;
  }
  if (tid < CSEG) {
    double a = 0.0, d = 0.0;
    for (int j2 = 0; j2 < TK; ++j2) {
      a += INm[j2 * CSEG + tid] * fvi[j2];
      d += OUTm[j2 * CSEG + tid] * fvo[j2];
    }
    avim[tid] = a; avom[tid] = d;
  }
  __syncthreads();
  double ci = fmax(s_sfvi, 1.0), co = fmax(s_sfvo, 1.0);
  if (tid < TK) {
    double d1 = 0.0, d2 = 0.0, d3 = 0.0, d4 = 0.0;
    for (int e = 0; e < CH; ++e) { d1 += OUT[tid * CH + e] * avi[e]; d2 += IN[tid * CH + e] * avo[e]; }
    for (int e = 0; e < CSEG; ++e) { d3 += OUTm[tid * CSEG + e] * avim[e]; d4 += INm[tid * CSEG + e] * avom[e]; }
    rm[tid] = d1 / ci; cm[tid] = d2 / co; rmm[tid] = d3 / ci; cmm[tid] = d4 / co;
  }
  __syncthreads();
  if (tid == 0) {
    double g = 0.0, gm = 0.0;
    for (int e = 0; e < CH; ++e) g += avo[e] * avi[e];
    for (int e = 0; e < CSEG; ++e) gm += avom[e] * avim[e];
    double den = fmax(s_sfvo * s_sfvi, 1.0);
    g /= den; gm /= den;
    double loss = 0.0;
    { // row beacon: sgn_mask = rmm>gm, sgn_dense = rm>g, vals = rm, v = fvo
      double s[4] = {0, 0, 0, 0}, cn[4] = {0, 0, 0, 0};
      for (int j2 = 0; j2 < TK; ++j2) {
        int smv = rmm[j2] > gm;
        int dmv = rm[j2] > g;
        int cat = smv ? (dmv ? 3 : 0) : (dmv ? 1 : 2);  // FP,FN,TP,TN = 0,1,2,3
        s[cat] += rm[j2] * fvo[j2];
        cn[cat] += fvo[j2];
      }
      const double sg[4] = {-1.0, 1.0, 1.0, -1.0};
      for (int t = 0; t < 4; ++t)
        if (cn[t] > 0.0) loss += sg[t] * (s[t] / fmax(cn[t], 1.0));
    }
    { // col beacon: sgn_mask = cmm>gm, sgn_dense = cm>g, vals = cm, v = fvi
      double s[4] = {0, 0, 0, 0}, cn[4] = {0, 0, 0, 0};
      for (int j2 = 0; j2 < TK; ++j2) {
        int smv = cmm[j2] > gm;
        int dmv = cm[j2] > g;
        int cat = smv ? (dmv ? 3 : 0) : (dmv ? 1 : 2);
        s[cat] += cm[j2] * fvi[j2];
        cn[cat] += fvi[j2];
      }
      const double sg[4] = {-1.0, 1.0, 1.0, -1.0};
      for (int t = 0; t < 4; ++t)
        if (cn[t] > 0.0) loss += sg[t] * (s[t] / fmax(cn[t], 1.0));
    }
    float lab = label[b * CSEG + c + 1];
    double gate = (s_sfvi >= 10.0 && s_sfvo >= 10.0 && lab > 0.f) ? 1.0 : 0.0;
    lossmap[mapi] = loss * gate;
  }
}

// ---------------- K6: deterministic ordered final sum --------------------------
__global__ __launch_bounds__(64) void k_final(const double* __restrict__ lossmap,
                                              float* __restrict__ out) {
  if (threadIdx.x == 0 && blockIdx.x == 0) {
    double s = 0.0;
    for (int i = 0; i < NMAP; ++i) s += lossmap[i];
    out[0] = (float)s;
  }
}

extern "C" void kernel_launch(void* const* d_in, const int* in_sizes, int n_in,
                              void* d_out, int out_size, void* d_ws, size_t ws_size,
                              hipStream_t stream) {
  const float* seg_map  = (const float*)d_in[0];
  const float* dense_ft = (const float*)d_in[1];
  const float* maskp    = (const float*)d_in[2];
  const float* label    = (const float*)d_in[3];
  float* outp = (float*)d_out;

  char* w = (char*)d_ws;
  unsigned long long* keys = (unsigned long long*)w; w += (size_t)NMAP * HW * 8;
  double* outs   = (double*)w;            w += (size_t)NMAP * TK * CH * 8;
  double* ins    = (double*)w;            w += (size_t)NMAP * TK * CH * 8;
  double* outs_m = (double*)w;            w += (size_t)NMAP * TK * CSEG * 8;
  double* ins_m  = (double*)w;            w += (size_t)NMAP * TK * CSEG * 8;
  double* lossmap = (double*)w;           w += (size_t)NMAP * 8;
  unsigned long long* ckey = (unsigned long long*)w; w += (size_t)NMAP * CAND * 8;
  int* cidx = (int*)w;                    w += (size_t)NMAP * CAND * 4;
  int* pos  = (int*)w;                    w += (size_t)NMAP * TK * 4;
  int* vout = (int*)w;                    w += (size_t)NMAP * TK * 4;
  int* vin  = (int*)w;                    w += (size_t)NMAP * TK * 4;
  unsigned char* qb = (unsigned char*)w;  w += (size_t)NMAP * HW;

  k_sobel<<<NMAP * PARTS, 256, 0, stream>>>(seg_map, label, qb, keys);
  k_select<<<NMAP * PARTS, 256, 0, stream>>>(keys, ckey, cidx);
  k_topk_merge<<<NMAP, 256, 0, stream>>>(ckey, cidx, pos);
  k_gather<<<NMAP * TK, 256, 0, stream>>>(dense_ft, maskp, qb, pos, outs, ins,
                                          outs_m, ins_m, vout, vin);
  k_stats<<<NMAP, 256, 0, stream>>>(outs, ins, outs_m, ins_m, vout, vin, label, lossmap);
  k_final<<<1, 64, 0, stream>>>(lossmap, outp);
}

// Round 18
// 175.409 us; speedup vs baseline: 1.8128x; 1.4962x over previous
//
#include <hip/hip_runtime.h>
#include <math.h>

#define HW 65536
#define WID 256
#define HEI 256
#define NB 2
#define NFG 20
#define NMAP 40
#define CH 256
#define CSEG 21
#define TK 100
#define PARTS 32
#define PARTN (HW / PARTS)    // 2048
#define RPP (HEI / PARTS)     // 8 rows per part
#define CAND (PARTS * TK)     // 3200
#define MCH 13                // ceil(CAND/256)

__device__ __constant__ float c_GX[25] = {
  2.f,1.f,1e-6f,-1.f,-2.f,
  3.f,2.f,1e-6f,-2.f,-3.f,
  4.f,3.f,0.f,-3.f,-4.f,
  3.f,2.f,1e-6f,-2.f,-3.f,
  2.f,1.f,1e-6f,-1.f,-2.f};
__device__ __constant__ float c_GY[25] = {
  2.f,3.f,4.f,3.f,2.f,
  1.f,2.f,3.f,2.f,1.f,
  1e-6f,1e-6f,1e-6f,1e-6f,1e-6f,
  -1.f,-2.f,-3.f,-2.f,-1.f,
  -2.f,-3.f,-4.f,-3.f,-2.f};

// ---------------- K1: softmax(seg_map * 1000, axis=ch)[:,1:] in f64 ------------
// Computed ONCE per (batch,pixel); shared by all 20 fg-maps downstream.
__global__ __launch_bounds__(256) void k_seg(const float* __restrict__ seg_map,
                                             double* __restrict__ seg) {
  int idx = blockIdx.x * blockDim.x + threadIdx.x;
  if (idx >= NB * HW) return;
  int b = idx / HW, p = idx % HW;
  double x[CSEG];
  double m = -INFINITY;
  #pragma unroll
  for (int c = 0; c < CSEG; ++c) {
    double v = (double)seg_map[(size_t)(b * CSEG + c) * HW + p] * 1000.0;
    x[c] = v;
    m = fmax(m, v);
  }
  double s = 0.0;
  #pragma unroll
  for (int c = 0; c < CSEG; ++c) {
    double d = x[c] - m;
    double e = (d < -746.0) ? 0.0 : exp(d);   // bit-identical to exp(d)
    x[c] = e; s += e;
  }
  #pragma unroll
  for (int c = 1; c < CSEG; ++c)
    seg[(size_t)(b * NFG + (c - 1)) * HW + p] = x[c] / s;
}

// ---------------- K2a: pure Sobel + quantize -> keys (no select, 1 barrier) -----
// Key = gx^2+gy^2+1e-8 (monotone in mag; values unused downstream). Bucket via
// sign logic + tan thresholds (endpoint/±0 semantics match atan2 intervals).
__global__ __launch_bounds__(256) void k_sobel(
    const double* __restrict__ seg, const float* __restrict__ label,
    unsigned char* __restrict__ qb, unsigned long long* __restrict__ keys) {
  int mapi = blockIdx.x / PARTS, part = blockIdx.x % PARTS;
  int tid = threadIdx.x;
  int row0 = part * RPP;
  const double* im = seg + (size_t)mapi * HW;

  __shared__ double tile[RPP + 4][WID];       // 24576 B

  for (int r = 0; r < RPP + 4; ++r) {
    int gr = row0 - 2 + r;
    tile[r][tid] = (gr >= 0 && gr < HEI) ? im[gr * WID + tid] : 0.0;
  }
  __syncthreads();

  int b = mapi / NFG, c = mapi % NFG;
  double lab = (double)label[b * CSEG + c + 1];
  const double DIVQ = 3.1416 / 8.0;
  double u1 = tan(DIVQ);                 // tan(T1)
  double u3 = tan(3.0 * DIVQ);           // tan(T3)
  double w5 = tan(M_PI - 5.0 * DIVQ);    // tan(pi - T5)
  double w7 = tan(M_PI - 7.0 * DIVQ);    // tan(pi - T7)

  #pragma unroll
  for (int k = 0; k < RPP; ++k) {
    double gx = 0.0, gy = 0.0;
    #pragma unroll
    for (int dy = 0; dy < 5; ++dy) {
      #pragma unroll
      for (int dx = 0; dx < 5; ++dx) {
        int xx = tid + dx - 2;
        double v = (xx >= 0 && xx < WID) ? tile[k + dy][xx] : 0.0;
        gx += v * (double)c_GX[dy * 5 + dx];
        gy += v * (double)c_GY[dy * 5 + dx];
      }
    }
    gx *= lab; gy *= lab;
    double rad2 = gx * gx + gy * gy + 1e-8;    // same expr order as sqrt version
    int qv;
    if (gx > 0.0) {                    // o in (-pi/2, pi/2)
      double t1 = u1 * gx, t3 = u3 * gx;
      if (gy >= t3) qv = 1;            // [T3, pi/2)
      else if (gy >= t1) qv = 0;       // [T1, T3)
      else if (gy >= -t1) qv = 7;      // [-T1, T1)
      else if (gy >= -t3) qv = 6;      // [-T3, -T1)
      else qv = 5;                     // (-pi/2, -T3)
    } else if (gx < 0.0) {
      double ag = -gx;
      if (gy >= 0.0) {                 // o in (pi/2, pi]  (gy=+-0 -> o=+-pi -> q3)
        if (gy <= w7 * ag) qv = 3;     // [T7, pi]
        else if (gy <= w5 * ag) qv = 2;// [T5, T7)
        else qv = 1;                   // (pi/2, T5)
      } else {                         // o in (-pi, -pi/2)
        double ay = -gy;
        if (ay < w7 * ag) qv = 3;      // (-pi, -T7)
        else if (ay < w5 * ag) qv = 4; // [-T7, -T5)
        else qv = 5;                   // [-T5, -pi/2)
      }
    } else {                           // gx == +0 (never -0 here)
      if (gy > 0.0) qv = 1;            // o = pi/2 in [T3, T5)
      else if (gy < 0.0) qv = 5;       // o = -pi/2 in [-T5, -T3)
      else qv = 7;                     // atan2(+-0, +0) = +-0 -> [-T1, T1)
    }
    size_t gp = (size_t)mapi * HW + (size_t)(row0 + k) * WID + tid;
    keys[gp] = (unsigned long long)__double_as_longlong(rad2);
    qb[gp] = (unsigned char)qv;
  }
}

// ---------------- K2b: per-part exact top-100 over precomputed keys -------------
// Aggregated atomics, early exit, 3 barriers/round; LDS key mirror for the
// index-ordered extraction. Numpy argsort[::-1] tie semantics.
__global__ __launch_bounds__(256) void k_select(
    const unsigned long long* __restrict__ keys,
    unsigned long long* __restrict__ ckey, int* __restrict__ cidx) {
  int mapi = blockIdx.x / PARTS, part = blockIdx.x % PARTS;
  int tid = threadIdx.x;
  int lane = tid & 63, w = tid >> 6;
  const unsigned long long* kp = keys + (size_t)mapi * HW + (size_t)part * PARTN;

  __shared__ unsigned long long sk[PARTN];    // 16384 B
  __shared__ unsigned int hist4[4][256];      // 4096 B
  __shared__ int wtot[4];
  __shared__ int s_r, s_cnt, s_bsel, s_selcnt;
  __shared__ unsigned long long s_kv;

  unsigned long long mykey[RPP];
  #pragma unroll
  for (int k = 0; k < RPP; ++k) {
    unsigned long long key = kp[k * 256 + tid];
    mykey[k] = key;
    sk[k * 256 + tid] = key;
  }
  hist4[0][tid] = 0; hist4[1][tid] = 0; hist4[2][tid] = 0; hist4[3][tid] = 0;
  if (tid == 0) { s_r = TK; s_cnt = 0; }
  __syncthreads();

  // ---- radix select of the 100th-largest key (aggregated atomics, early exit)
  unsigned long long pfx = 0ull, msk = 0ull;
  int early = 0;
  for (int round = 0; round < 8; ++round) {
    int shift = 56 - 8 * round;
    int curb = -1; unsigned int curc = 0;
    #pragma unroll
    for (int k = 0; k < RPP; ++k) {
      unsigned long long key = mykey[k];
      int bk = ((key & msk) == pfx) ? (int)((key >> shift) & 0xFF) : -1;
      if (bk == curb) { ++curc; }
      else {
        if (curb >= 0) atomicAdd(&hist4[w][curb], curc);
        curb = bk; curc = 1;
      }
    }
    if (curb >= 0) atomicAdd(&hist4[w][curb], curc);
    __syncthreads();               // B1: atomics visible
    int r = s_r;
    int cnt = (int)(hist4[0][tid] + hist4[1][tid] + hist4[2][tid] + hist4[3][tid]);
    hist4[0][tid] = 0; hist4[1][tid] = 0; hist4[2][tid] = 0; hist4[3][tid] = 0;
    int v = cnt;
    #pragma unroll
    for (int off = 1; off < 64; off <<= 1) {   // wave inclusive SUFFIX scan
      int u = __shfl_down(v, off, 64);
      if (lane + off < 64) v += u;
    }
    if (lane == 0) wtot[w] = v;
    __syncthreads();               // B2: wtot visible
    int add = 0;
    for (int ww = w + 1; ww < 4; ++ww) add += wtot[ww];
    v += add;                      // inclusive suffix over all 256 bins
    if (v >= r && v - cnt < r) { s_bsel = tid; s_r = r - (v - cnt); s_selcnt = cnt; }
    __syncthreads();               // B3: s_bsel/s_r/s_selcnt visible
    pfx |= ((unsigned long long)s_bsel << shift);
    msk |= (0xFFull << shift);
    if (s_selcnt == 1) { early = 1; break; }   // cutoff prefix unique -> done
  }
  if (early) {
    #pragma unroll
    for (int k = 0; k < RPP; ++k)
      if ((mykey[k] & msk) == pfx) s_kv = mykey[k];   // exactly one writer
    __syncthreads();
  } else {
    if (tid == 0) s_kv = pfx;      // full 64-bit prefix = exact value
    __syncthreads();
  }
  unsigned long long kv = s_kv;
  int need_eq = s_r;               // >= 1

  // ---- emit candidates: strictly-greater (any order) + largest-index equals
  unsigned long long* outk = ckey + (size_t)mapi * CAND + (size_t)part * TK;
  int* outi = cidx + (size_t)mapi * CAND + (size_t)part * TK;
  int gbase = part * PARTN;
  const int CHN = PARTN / 256;     // 8, contiguous chunk per thread (index order)
  int base = tid * CHN;
  int myeq = 0;
  for (int k = 0; k < CHN; ++k) {
    unsigned long long key = sk[base + k];
    if (key > kv) {
      int slot = atomicAdd(&s_cnt, 1);
      outk[slot] = key; outi[slot] = gbase + base + k;
    } else if (key == kv) ++myeq;
  }
  int v2 = myeq;                   // ascending inclusive scan over 256 threads
  #pragma unroll
  for (int off = 1; off < 64; off <<= 1) {
    int u = __shfl_up(v2, off, 64);
    if (lane >= off) v2 += u;
  }
  if (lane == 63) wtot[w] = v2;
  __syncthreads();
  int addl = 0;
  for (int ww = 0; ww < w; ++ww) addl += wtot[ww];
  int incl = v2 + addl;
  int rank = incl - myeq;          // exclusive prefix = ascending-index rank
  int eqtot = wtot[0] + wtot[1] + wtot[2] + wtot[3];
  int lo = eqtot - need_eq;        // keep equals with rank >= lo (largest indices)
  int wb = TK - need_eq;
  for (int k = 0; k < CHN; ++k) {
    unsigned long long key = sk[base + k];
    if (key == kv) {
      if (rank >= lo) { outk[wb + rank - lo] = key; outi[wb + rank - lo] = gbase + base + k; }
      ++rank;
    }
  }
}

// ---------------- K3b: merge 3200 candidates -> exact global top-100 ------------
__global__ __launch_bounds__(256) void k_topk_merge(
    const unsigned long long* __restrict__ ckey,
    const int* __restrict__ cidx, int* __restrict__ pos) {
  int mapi = blockIdx.x, tid = threadIdx.x;
  int lane = tid & 63, w = tid >> 6;
  __shared__ unsigned long long k_[CAND];       // 25.6 KiB
  __shared__ int i_[CAND];                      // 12.8 KiB
  __shared__ int eqi[CAND];                     // 12.8 KiB
  __shared__ unsigned int hist4[4][256];
  __shared__ int wtot[4];
  __shared__ int s_r, s_cnt, s_eqn, s_bsel, s_selcnt, s_w2;
  __shared__ unsigned long long s_kv;
  for (int c = tid; c < CAND; c += 256) {
    k_[c] = ckey[(size_t)mapi * CAND + c];
    i_[c] = cidx[(size_t)mapi * CAND + c];
  }
  hist4[0][tid] = 0; hist4[1][tid] = 0; hist4[2][tid] = 0; hist4[3][tid] = 0;
  if (tid == 0) { s_r = TK; s_cnt = 0; s_eqn = 0; s_w2 = 0; }
  __syncthreads();
  unsigned long long pfx = 0ull, msk = 0ull;
  int early = 0;
  int mbase = tid * MCH;           // contiguous chunk -> equal keys form runs
  for (int round = 0; round < 8; ++round) {
    int shift = 56 - 8 * round;
    int curb = -1; unsigned int curc = 0;
    for (int t = 0; t < MCH; ++t) {
      int cc = mbase + t;
      int bk = -1;
      if (cc < CAND) {
        unsigned long long key = k_[cc];
        if ((key & msk) == pfx) bk = (int)((key >> shift) & 0xFF);
      }
      if (bk == curb) { ++curc; }
      else {
        if (curb >= 0) atomicAdd(&hist4[w][curb], curc);
        curb = bk; curc = 1;
      }
    }
    if (curb >= 0) atomicAdd(&hist4[w][curb], curc);
    __syncthreads();               // B1
    int r = s_r;
    int cnt = (int)(hist4[0][tid] + hist4[1][tid] + hist4[2][tid] + hist4[3][tid]);
    hist4[0][tid] = 0; hist4[1][tid] = 0; hist4[2][tid] = 0; hist4[3][tid] = 0;
    int v = cnt;
    #pragma unroll
    for (int off = 1; off < 64; off <<= 1) {
      int u = __shfl_down(v, off, 64);
      if (lane + off < 64) v += u;
    }
    if (lane == 0) wtot[w] = v;
    __syncthreads();               // B2
    int add = 0;
    for (int ww = w + 1; ww < 4; ++ww) add += wtot[ww];
    v += add;
    if (v >= r && v - cnt < r) { s_bsel = tid; s_r = r - (v - cnt); s_selcnt = cnt; }
    __syncthreads();               // B3
    pfx |= ((unsigned long long)s_bsel << shift);
    msk |= (0xFFull << shift);
    if (s_selcnt == 1) { early = 1; break; }
  }
  if (early) {
    for (int c = tid; c < CAND; c += 256)
      if ((k_[c] & msk) == pfx) s_kv = k_[c];
    __syncthreads();
  } else {
    if (tid == 0) s_kv = pfx;
    __syncthreads();
  }
  unsigned long long kv = s_kv;
  int need_eq = s_r;
  for (int c = tid; c < CAND; c += 256) {
    unsigned long long key = k_[c];
    if (key > kv) {
      int slot = atomicAdd(&s_cnt, 1);
      pos[mapi * TK + slot] = i_[c];            // set semantics; order irrelevant
    } else if (key == kv) {
      int e = atomicAdd(&s_eqn, 1);
      eqi[e] = i_[c];
    }
  }
  __syncthreads();
  int eqn = s_eqn;
  int wb = TK - need_eq;
  if (eqn == need_eq) {            // all equals belong
    for (int e = tid; e < eqn; e += 256) pos[mapi * TK + wb + e] = eqi[e];
    return;
  }
  // exact 2-round radix select of the need_eq-th largest INDEX among equals
  if (tid == 0) s_r = need_eq;
  __syncthreads();
  unsigned int ipfx = 0u, imsk = 0u;
  for (int round = 0; round < 2; ++round) {
    int shift = 8 * (1 - round);
    for (int e = tid; e < eqn; e += 256) {
      unsigned int iv = (unsigned int)eqi[e];
      if ((iv & imsk) == ipfx)
        atomicAdd(&hist4[w][(iv >> shift) & 0xFFu], 1u);
    }
    __syncthreads();               // B1
    int r = s_r;
    int cnt = (int)(hist4[0][tid] + hist4[1][tid] + hist4[2][tid] + hist4[3][tid]);
    hist4[0][tid] = 0; hist4[1][tid] = 0; hist4[2][tid] = 0; hist4[3][tid] = 0;
    int v = cnt;
    #pragma unroll
    for (int off = 1; off < 64; off <<= 1) {
      int u = __shfl_down(v, off, 64);
      if (lane + off < 64) v += u;
    }
    if (lane == 0) wtot[w] = v;
    __syncthreads();               // B2
    int add = 0;
    for (int ww = w + 1; ww < 4; ++ww) add += wtot[ww];
    v += add;
    if (v >= r && v - cnt < r) { s_bsel = tid; s_r = r - (v - cnt); }
    __syncthreads();               // B3
    ipfx |= ((unsigned int)s_bsel << shift);
    imsk |= (0xFFu << shift);
  }
  int thrIdx = (int)ipfx;          // need_eq-th largest index; distinct -> exact
  for (int e = tid; e < eqn; e += 256) {
    if (eqi[e] >= thrIdx) {
      int slot = atomicAdd(&s_w2, 1);
      pos[mapi * TK + wb + slot] = eqi[e];
    }
  }
}

// ---------------- K4: gather + per-column f64 softmax, one wave per softmax -----
__global__ __launch_bounds__(256) void k_gather(
    const float* __restrict__ dense_ft, const float* __restrict__ maskp,
    const unsigned char* __restrict__ qb, const int* __restrict__ pos,
    double* __restrict__ outs, double* __restrict__ ins,
    double* __restrict__ outs_m, double* __restrict__ ins_m,
    int* __restrict__ voutArr, int* __restrict__ vinArr) {
  int blk = blockIdx.x;
  int mapi = blk / TK, j = blk % TK;
  int b = mapi / NFG;
  int tid = threadIdx.x;
  int lane = tid & 63, w = tid >> 6;
  int p = pos[mapi * TK + j];
  int o = (int)qb[(size_t)mapi * HW + p] + 1;
  int mod4 = ((o & 3) == 0) ? 1 : 0;
  int horiz = (o == 2 || o == 6) ? 1 : 0;
  int po = (o < 4) ? 25 : -5;   // STEP*STEP : -STEP
  int pi = (o < 4) ? -5 : 1;
  int so = ((o & 1) == 0) ? -1 : 1;
  int si = -so;
  int out_idx = p + po * mod4 * WID + so * horiz;
  int in_idx  = p + pi * mod4 * WID + si * horiz;
  int ro = out_idx % 255; if (ro < 0) ro += 255;   // python floored mod
  int ri = in_idx  % 255; if (ri < 0) ri += 255;
  int vo = (ro != 0 && ro != 1 && out_idx > 0 && out_idx < HW - 1) ? 1 : 0;
  int vi = (ri != 0 && ri != 1 && in_idx  > 0 && in_idx  < HW - 1) ? 1 : 0;
  int oi = out_idx < 0 ? 0 : (out_idx > HW - 1 ? HW - 1 : out_idx);
  int ii = in_idx  < 0 ? 0 : (in_idx  > HW - 1 ? HW - 1 : in_idx);
  if (tid == 0) { voutArr[mapi * TK + j] = vo; vinArr[mapi * TK + j] = vi; }

  if (w < 2) {
    int idx = (w == 0) ? oi : ii;
    double x[4];
    double mx = -INFINITY;
    #pragma unroll
    for (int q = 0; q < 4; ++q) {
      x[q] = (double)dense_ft[(size_t)(b * CH + lane + 64 * q) * HW + idx];
      mx = fmax(mx, x[q]);
    }
    #pragma unroll
    for (int off = 1; off < 64; off <<= 1) mx = fmax(mx, __shfl_xor(mx, off, 64));
    double e[4], s = 0.0;
    #pragma unroll
    for (int q = 0; q < 4; ++q) { e[q] = exp(x[q] - mx); s += e[q]; }
    #pragma unroll
    for (int off = 1; off < 64; off <<= 1) s += __shfl_xor(s, off, 64);
    double* dst = ((w == 0) ? outs : ins) + ((size_t)mapi * TK + j) * CH;
    #pragma unroll
    for (int q = 0; q < 4; ++q) dst[lane + 64 * q] = e[q] / s;
  } else {
    int idx = (w == 2) ? oi : ii;
    double y = (lane < CSEG) ? (double)maskp[(size_t)(b * CSEG + lane) * HW + idx]
                             : -INFINITY;
    double mx = y;
    #pragma unroll
    for (int off = 1; off < 64; off <<= 1) mx = fmax(mx, __shfl_xor(mx, off, 64));
    double e = (lane < CSEG) ? exp(y - mx) : 0.0;
    double s = e;
    #pragma unroll
    for (int off = 1; off < 64; off <<= 1) s += __shfl_xor(s, off, 64);
    if (lane < CSEG)
      (((w == 2) ? outs_m : ins_m) + ((size_t)mapi * TK + j) * CSEG)[lane] = e / s;
  }
}

// ---------------- K5: per-map statistics + beacon in f64 (sim never materialized)
__global__ __launch_bounds__(256) void k_stats(
    const double* __restrict__ outs, const double* __restrict__ ins,
    const double* __restrict__ outs_m, const double* __restrict__ ins_m,
    const int* __restrict__ voutArr, const int* __restrict__ vinArr,
    const float* __restrict__ label, double* __restrict__ lossmap) {
  int mapi = blockIdx.x, tid = threadIdx.x;
  int b = mapi / NFG, c = mapi % NFG;
  __shared__ double fvo[TK], fvi[TK];
  __shared__ double avi[CH], avo[CH], avim[CSEG], avom[CSEG];
  __shared__ double rm[TK], cm[TK], rmm[TK], cmm[TK];
  __shared__ double s_sfvo, s_sfvi;
  if (tid < TK) {
    fvo[tid] = (double)voutArr[mapi * TK + tid];
    fvi[tid] = (double)vinArr[mapi * TK + tid];
  }
  __syncthreads();
  if (tid == 0) {
    double a = 0.0, d = 0.0;
    for (int j2 = 0; j2 < TK; ++j2) { a += fvo[j2]; d += fvi[j2]; }
    s_sfvo = a; s_sfvi = d;
  }
  const double* OUT  = outs   + (size_t)mapi * TK * CH;
  const double* IN   = ins    + (size_t)mapi * TK * CH;
  const double* OUTm = outs_m + (size_t)mapi * TK * CSEG;
  const double* INm  = ins_m  + (size_t)mapi * TK * CSEG;
  {
    double a = 0.0, d = 0.0;
    for (int j2 = 0; j2 < TK; ++j2) {
      a += IN[j2 * CH + tid] * fvi[j2];
      d += OUT[j2 * CH + tid] * fvo[j2];
    }
    avi[tid] = a; avo[tid] = d;
  }
  if (tid < CSEG) {
    double a = 0.0, d = 0.0;
    for (int j2 = 0; j2 < TK; ++j2) {
      a += INm[j2 * CSEG + tid] * fvi[j2];
      d += OUTm[j2 * CSEG + tid] * fvo[j2];
    }
    avim[tid] = a; avom[tid] = d;
  }
  __syncthreads();
  double ci = fmax(s_sfvi, 1.0), co = fmax(s_sfvo, 1.0);
  if (tid < TK) {
    double d1 = 0.0, d2 = 0.0, d3 = 0.0, d4 = 0.0;
    for (int e = 0; e < CH; ++e) { d1 += OUT[tid * CH + e] * avi[e]; d2 += IN[tid * CH + e] * avo[e]; }
    for (int e = 0; e < CSEG; ++e) { d3 += OUTm[tid * CSEG + e] * avim[e]; d4 += INm[tid * CSEG + e] * avom[e]; }
    rm[tid] = d1 / ci; cm[tid] = d2 / co; rmm[tid] = d3 / ci; cmm[tid] = d4 / co;
  }
  __syncthreads();
  if (tid == 0) {
    double g = 0.0, gm = 0.0;
    for (int e = 0; e < CH; ++e) g += avo[e] * avi[e];
    for (int e = 0; e < CSEG; ++e) gm += avom[e] * avim[e];
    double den = fmax(s_sfvo * s_sfvi, 1.0);
    g /= den; gm /= den;
    double loss = 0.0;
    { // row beacon: sgn_mask = rmm>gm, sgn_dense = rm>g, vals = rm, v = fvo
      double s[4] = {0, 0, 0, 0}, cn[4] = {0, 0, 0, 0};
      for (int j2 = 0; j2 < TK; ++j2) {
        int smv = rmm[j2] > gm;
        int dmv = rm[j2] > g;
        int cat = smv ? (dmv ? 3 : 0) : (dmv ? 1 : 2);  // FP,FN,TP,TN = 0,1,2,3
        s[cat] += rm[j2] * fvo[j2];
        cn[cat] += fvo[j2];
      }
      const double sg[4] = {-1.0, 1.0, 1.0, -1.0};
      for (int t = 0; t < 4; ++t)
        if (cn[t] > 0.0) loss += sg[t] * (s[t] / fmax(cn[t], 1.0));
    }
    { // col beacon: sgn_mask = cmm>gm, sgn_dense = cm>g, vals = cm, v = fvi
      double s[4] = {0, 0, 0, 0}, cn[4] = {0, 0, 0, 0};
      for (int j2 = 0; j2 < TK; ++j2) {
        int smv = cmm[j2] > gm;
        int dmv = cm[j2] > g;
        int cat = smv ? (dmv ? 3 : 0) : (dmv ? 1 : 2);
        s[cat] += cm[j2] * fvi[j2];
        cn[cat] += fvi[j2];
      }
      const double sg[4] = {-1.0, 1.0, 1.0, -1.0};
      for (int t = 0; t < 4; ++t)
        if (cn[t] > 0.0) loss += sg[t] * (s[t] / fmax(cn[t], 1.0));
    }
    float lab = label[b * CSEG + c + 1];
    double gate = (s_sfvi >= 10.0 && s_sfvo >= 10.0 && lab > 0.f) ? 1.0 : 0.0;
    lossmap[mapi] = loss * gate;
  }
}

// ---------------- K6: deterministic ordered final sum --------------------------
__global__ __launch_bounds__(64) void k_final(const double* __restrict__ lossmap,
                                              float* __restrict__ out) {
  if (threadIdx.x == 0 && blockIdx.x == 0) {
    double s = 0.0;
    for (int i = 0; i < NMAP; ++i) s += lossmap[i];
    out[0] = (float)s;
  }
}

extern "C" void kernel_launch(void* const* d_in, const int* in_sizes, int n_in,
                              void* d_out, int out_size, void* d_ws, size_t ws_size,
                              hipStream_t stream) {
  const float* seg_map  = (const float*)d_in[0];
  const float* dense_ft = (const float*)d_in[1];
  const float* maskp    = (const float*)d_in[2];
  const float* label    = (const float*)d_in[3];
  float* outp = (float*)d_out;

  char* w = (char*)d_ws;
  double* seg = (double*)w;               w += (size_t)NB * NFG * HW * 8;
  unsigned long long* keys = (unsigned long long*)w; w += (size_t)NMAP * HW * 8;
  double* outs   = (double*)w;            w += (size_t)NMAP * TK * CH * 8;
  double* ins    = (double*)w;            w += (size_t)NMAP * TK * CH * 8;
  double* outs_m = (double*)w;            w += (size_t)NMAP * TK * CSEG * 8;
  double* ins_m  = (double*)w;            w += (size_t)NMAP * TK * CSEG * 8;
  double* lossmap = (double*)w;           w += (size_t)NMAP * 8;
  unsigned long long* ckey = (unsigned long long*)w; w += (size_t)NMAP * CAND * 8;
  int* cidx = (int*)w;                    w += (size_t)NMAP * CAND * 4;
  int* pos  = (int*)w;                    w += (size_t)NMAP * TK * 4;
  int* vout = (int*)w;                    w += (size_t)NMAP * TK * 4;
  int* vin  = (int*)w;                    w += (size_t)NMAP * TK * 4;
  unsigned char* qb = (unsigned char*)w;  w += (size_t)NMAP * HW;

  k_seg<<<(NB * HW + 255) / 256, 256, 0, stream>>>(seg_map, seg);
  k_sobel<<<NMAP * PARTS, 256, 0, stream>>>(seg, label, qb, keys);
  k_select<<<NMAP * PARTS, 256, 0, stream>>>(keys, ckey, cidx);
  k_topk_merge<<<NMAP, 256, 0, stream>>>(ckey, cidx, pos);
  k_gather<<<NMAP * TK, 256, 0, stream>>>(dense_ft, maskp, qb, pos, outs, ins,
                                          outs_m, ins_m, vout, vin);
  k_stats<<<NMAP, 256, 0, stream>>>(outs, ins, outs_m, ins_m, vout, vin, label, lossmap);
  k_final<<<1, 64, 0, stream>>>(lossmap, outp);
}